// Round 9
// baseline (90.110 us; speedup 1.0000x reference)
//
#include <hip/hip_runtime.h>
#include <math.h>

#define HW 16384
#define NC 64
#define NB 16

// ev/et: plain row-major bf16 [1024 rows][16384 k], ev in d_out[0,32MB),
// et in d_out[32MB,64MB). (d_out fully overwritten by enhance afterwards.)
// ws layout (floats):
//   [0,1024) S_v   [1024,2048) S_t   [2048,3072) U_t   [3072,4096) gw
//   [4096, 4096+npart*65536) J_raw partial copies

typedef __attribute__((ext_vector_type(8))) short bf16x8;
typedef __attribute__((ext_vector_type(4))) float f32x4;

__device__ inline unsigned short f2bf(float x) {
  union { float f; unsigned u; } v; v.f = x;
  unsigned r = v.u + 0x7FFFu + ((v.u >> 16) & 1u);   // RNE; exp>0 so no NaN
  return (unsigned short)(r >> 16);
}

__device__ inline float wave_reduce_sum(float v) {
#pragma unroll
  for (int o = 32; o > 0; o >>= 1) v += __shfl_down(v, o, 64);
  return v;
}

__device__ inline int lds_off(int r, int ko) {       // ushort units
  return r * 64 + ((ko ^ (r & 7)) << 3);
}

#if __has_builtin(__builtin_amdgcn_global_load_lds)
__device__ inline void gload16(const void* g, void* l) {
  __builtin_amdgcn_global_load_lds(
      (const __attribute__((address_space(1))) void*)g,
      (__attribute__((address_space(3))) void*)l, 16, 0, 0);
}
#else
__device__ inline void gload16(const void* g, void* l) {
  ((float*)l)[0] = 0.f;   // unused fallback
}
#endif

// -------- pass 1: fully-linear streaming transform (enhance clone) ---------
// Wave (r, seg): 8 iters over its 8KB row segment; reads 2x16B/lane contig,
// writes 2x8B/lane contig (512B/instr). Stats in regs, 1 reduce + 3 atomics.
__global__ __launch_bounds__(256) void transform_linear(const float* __restrict__ vis,
                                                        const float* __restrict__ text,
                                                        ushort* __restrict__ ev,
                                                        ushort* __restrict__ et,
                                                        float* __restrict__ ws) {
  const int t = threadIdx.x, w = t >> 6, l = t & 63;
  const int W = blockIdx.x * 4 + w;     // global wave 0..8191
  const int r = W >> 3;                 // row 0..1023
  const int seg = W & 7;
  const int b = r >> 6, c = r & 63;

  const float* vrow = vis  + (size_t)r * HW + seg * 2048;
  const float* trow = text + (size_t)r * HW + seg * 2048;
  ushort* evp = ev + (size_t)r * HW + seg * 2048;
  ushort* etp = et + (size_t)r * HW + seg * 2048;

  float sv = 0.f, st = 0.f, ut = 0.f;

  f32x4 pv = *(const f32x4*)(vrow + l * 4);
  f32x4 px = *(const f32x4*)(trow + l * 4);
#pragma unroll
  for (int it = 0; it < 8; ++it) {
    f32x4 v = pv, x = px;
    if (it + 1 < 8) {                    // prefetch next iter
      pv = *(const f32x4*)(vrow + (it + 1) * 256 + l * 4);
      px = *(const f32x4*)(trow + (it + 1) * 256 + l * 4);
    }
    float e0 = __expf(v[0]), e1 = __expf(v[1]), e2 = __expf(v[2]), e3 = __expf(v[3]);
    float g0 = __expf(x[0]), g1 = __expf(x[1]), g2 = __expf(x[2]), g3 = __expf(x[3]);
    sv += (e0 + e1) + (e2 + e3);
    st += (g0 + g1) + (g2 + g3);
    ut += (g0 * x[0] + g1 * x[1]) + (g2 * x[2] + g3 * x[3]);
    ushort4 qv = make_ushort4(f2bf(e0), f2bf(e1), f2bf(e2), f2bf(e3));
    ushort4 qt = make_ushort4(f2bf(g0), f2bf(g1), f2bf(g2), f2bf(g3));
    *reinterpret_cast<ushort4*>(evp + it * 256 + l * 4) = qv;
    *reinterpret_cast<ushort4*>(etp + it * 256 + l * 4) = qt;
  }

  sv = wave_reduce_sum(sv);
  st = wave_reduce_sum(st);
  ut = wave_reduce_sum(ut);
  if (l == 0) {
    atomicAdd(&ws[        b * 64 + c], sv);
    atomicAdd(&ws[1024 + b * 64 + c], st);
    atomicAdd(&ws[2048 + b * 64 + c], ut);
  }
}

// ---- pass 2: MFMA GEMM staging 64x64 tiles from row-major bf16 (L3-hot) ----
// Per k-step q: stage [64 rows][64 k] bf16 per tensor into slot q&3.
// gload16: lane l covers row 8i+(l>>3), 16B at k-slot (l&7)^((l>>3)&7)
// -> linear LDS dest receives XOR-swizzled content (R2/R6-verified layout).
#define PISSUE(q) do {                                                   \
    const int k0_ = kbase + (q) * 64;                                    \
    ushort* d_ = (ushort*)sl[(q) & 3];                                   \
    _Pragma("unroll") for (int i = 0; i < 8; ++i) {                      \
      const size_t rr_ = (size_t)(rowb + i * 8 + (l >> 3));              \
      const int kk_ = k0_ + (((l & 7) ^ (l >> 3)) << 3);                 \
      gload16(evg + rr_ * HW + kk_, d_ + i * 512 + l * 8);               \
      gload16(etg + rr_ * HW + kk_, d_ + 4096 + i * 512 + l * 8);        \
    }                                                                    \
  } while (0)

#define JSTEP(p, VMC, DO_ISSUE) do {                                     \
    asm volatile("s_waitcnt vmcnt(" VMC ")" ::: "memory");               \
    __builtin_amdgcn_sched_barrier(0);                                   \
    __builtin_amdgcn_s_barrier();                                        \
    DO_ISSUE;                                                            \
    const ushort* EVp = sl[(p) & 3];                                     \
    const ushort* ETp = EVp + 4096;                                      \
    bf16x8 af[4][2];                                                     \
    _Pragma("unroll") for (int fi = 0; fi < 4; ++fi) {                   \
      af[fi][0] = *(const bf16x8*)&EVp[lds_off(fi * 16 + m16, ks0)];     \
      af[fi][1] = *(const bf16x8*)&EVp[lds_off(fi * 16 + m16, ks0 + 4)]; \
    }                                                                    \
    bf16x8 bf0 = *(const bf16x8*)&ETp[lds_off(w * 16 + m16, ks0)];       \
    bf16x8 bf1 = *(const bf16x8*)&ETp[lds_off(w * 16 + m16, ks0 + 4)];   \
    asm volatile("s_waitcnt lgkmcnt(0)" ::: "memory");                   \
    __builtin_amdgcn_sched_barrier(0);                                   \
    _Pragma("unroll") for (int fi = 0; fi < 4; ++fi) {                   \
      acc[fi] = __builtin_amdgcn_mfma_f32_16x16x32_bf16(af[fi][0], bf0, acc[fi], 0, 0, 0); \
      acc[fi] = __builtin_amdgcn_mfma_f32_16x16x32_bf16(af[fi][1], bf1, acc[fi], 0, 0, 0); \
    }                                                                    \
  } while (0)

__global__ __launch_bounds__(256) void jgemm(const ushort* __restrict__ ev,
                                             const ushort* __restrict__ et,
                                             float* __restrict__ ws, int jmask) {
  const int b = blockIdx.x >> 5, chunk = blockIdx.x & 31;   // 512 blocks
  const int t = threadIdx.x, w = t >> 6, l = t & 63;
  const int m16 = l & 15, ks0 = l >> 4;
  const int rowb = b * 64;
  const int kbase = chunk * 512;

  __shared__ ushort sl[4][8192];        // 4 slots x (ev tile | et tile)

  const ushort* evg = ev;
  const ushort* etg = et;

  f32x4 acc[4];
#pragma unroll
  for (int i = 0; i < 4; ++i) acc[i] = (f32x4){0.f, 0.f, 0.f, 0.f};

  PISSUE(0); PISSUE(1); PISSUE(2);      // 48 loads in flight

  JSTEP(0, "32", PISSUE(3));
  JSTEP(1, "32", PISSUE(4));
  JSTEP(2, "32", PISSUE(5));
  JSTEP(3, "32", PISSUE(6));
  JSTEP(4, "32", PISSUE(7));
  JSTEP(5, "32", (void)0);
  JSTEP(6, "16", (void)0);
  JSTEP(7, "0",  (void)0);

  // C/D layout: col = l&15, row = (l>>4)*4 + reg (verified R2/R4/R5/R7)
  float* Jp = ws + 4096 + (size_t)((chunk & jmask) * NB + b) * 4096;
  const int q4 = (l >> 4) * 4;
#pragma unroll
  for (int fi = 0; fi < 4; ++fi)
#pragma unroll
    for (int r = 0; r < 4; ++r)
      atomicAdd(&Jp[(fi * 16 + q4 + r) * 64 + w * 16 + m16], acc[fi][r]);
}

// ---------------- pass 3: MI + guide weights -------------------------------
__global__ __launch_bounds__(256) void mi_gw_kernel(const float* __restrict__ ws,
                                                    float* __restrict__ gw,
                                                    int npart) {
  const int b = blockIdx.x, t = threadIdx.x;
  __shared__ float sSv[64], sSt[64];
  if (t < 64) sSv[t] = ws[b * 64 + t];
  else if (t < 128) sSt[t - 64] = ws[1024 + b * 64 + (t - 64)];
  __syncthreads();

  f32x4 jr0 = {0,0,0,0}, jr1 = {0,0,0,0}, jr2 = {0,0,0,0}, jr3 = {0,0,0,0};
  const float* base = ws + 4096 + (size_t)b * 4096 + t * 16;
  for (int p = 0; p < npart; ++p) {
    const f32x4* cp = (const f32x4*)(base + (size_t)p * (NB * 4096));
    jr0 += cp[0]; jr1 += cp[1]; jr2 += cp[2]; jr3 += cp[3];
  }

  const float HW2 = (float)HW * (float)HW;
  const float fv = HW2 / sSv[t >> 2];
  const int d0 = (t & 3) * 16;
  float part = 0.f;
#pragma unroll
  for (int j = 0; j < 16; ++j) {
    float jv = (j < 4) ? jr0[j] : (j < 8) ? jr1[j - 4] : (j < 12) ? jr2[j - 8] : jr3[j - 12];
    float q = jv * (fv / sSt[d0 + j]);
    part += q * __logf(q + 1e-9f);
  }
  part = wave_reduce_sum(part);
  __shared__ float sh[4];
  __shared__ float mi_sh;
  int wid = t >> 6, lane = t & 63;
  if (lane == 0) sh[wid] = part;
  __syncthreads();
  if (t == 0) mi_sh = ((sh[0] + sh[1]) + (sh[2] + sh[3])) / HW2;
  __syncthreads();
  if (t < 64) {
    float S = sSt[t];
    float U = ws[2048 + b * 64 + t];
    float ent = __logf(S) - U / S;               // text spatial entropy
    float z = 1.0f - ent + 0.5f * mi_sh;
    gw[b * 64 + t] = 1.0f / (1.0f + __expf(-z));
  }
}

// ---------------- pass 4: enhance ------------------------------------------
__global__ __launch_bounds__(256) void enhance_kernel(const float4* __restrict__ vis,
                                                      const float4* __restrict__ text,
                                                      const float* __restrict__ gw,
                                                      float4* __restrict__ out) {
  const size_t total4 = (size_t)NB * NC * HW / 4;   // 4194304
  for (size_t i = (size_t)blockIdx.x * 256 + threadIdx.x; i < total4;
       i += (size_t)gridDim.x * 256) {
    float4 v = vis[i];
    float4 t = text[i];
    float g = gw[i >> 12];              // 4096 float4 per (b,c) row
    out[i] = make_float4(v.x + g * t.x, v.y + g * t.y,
                         v.z + g * t.z, v.w + g * t.w);
  }
}

extern "C" void kernel_launch(void* const* d_in, const int* in_sizes, int n_in,
                              void* d_out, int out_size, void* d_ws, size_t ws_size,
                              hipStream_t stream) {
  const float* vis  = (const float*)d_in[0];
  const float* text = (const float*)d_in[1];
  float* out = (float*)d_out;
  float* ws  = (float*)d_ws;
  float* gw  = ws + 3072;

  // d_out doubles as the bf16 exp matrices (fully overwritten by enhance)
  ushort* ev = (ushort*)d_out;
  ushort* et = ev + (size_t)1024 * HW;   // +32 MB

  size_t ws_floats = ws_size / sizeof(float);
  int npart = 1;
  if      (ws_floats >= 4096 + 4 * 65536) npart = 4;
  else if (ws_floats >= 4096 + 2 * 65536) npart = 2;

  hipMemsetAsync(ws, 0, (4096 + (size_t)npart * 65536) * sizeof(float), stream);

  transform_linear<<<2048, 256, 0, stream>>>(vis, text, ev, et, ws);
  jgemm<<<512, 256, 0, stream>>>(ev, et, ws, npart - 1);
  mi_gw_kernel<<<NB, 256, 0, stream>>>(ws, gw, npart);
  enhance_kernel<<<2048, 256, 0, stream>>>((const float4*)vis, (const float4*)text,
                                           gw, (float4*)out);
}

// Round 10
// 89.180 us; speedup vs baseline: 1.0104x; 1.0104x over previous
//
#include <hip/hip_runtime.h>
#include <math.h>

#define HW 16384
#define NC 64
#define NB 16

// ev/et: plain row-major bf16 [1024 rows][16384 k], ev in d_out[0,32MB),
// et in d_out[32MB,64MB). (d_out fully overwritten by enhance afterwards.)
// ws layout (floats):
//   [0,1024) S_v   [1024,2048) S_t   [2048,3072) U_t   [3072,4096) gw
//   [4096, 4096+npart*65536) J_raw partial copies

typedef __attribute__((ext_vector_type(8))) short bf16x8;
typedef __attribute__((ext_vector_type(8))) unsigned short u16x8;
typedef __attribute__((ext_vector_type(4))) float f32x4;

__device__ inline unsigned short f2bf(float x) {
  union { float f; unsigned u; } v; v.f = x;
  unsigned r = v.u + 0x7FFFu + ((v.u >> 16) & 1u);   // RNE; exp>0 so no NaN
  return (unsigned short)(r >> 16);
}

__device__ inline float wave_reduce_sum(float v) {
#pragma unroll
  for (int o = 32; o > 0; o >>= 1) v += __shfl_down(v, o, 64);
  return v;
}

__device__ inline int lds_off(int r, int ko) {       // ushort units
  return r * 64 + ((ko ^ (r & 7)) << 3);
}

#if __has_builtin(__builtin_amdgcn_global_load_lds)
__device__ inline void gload16(const void* g, void* l) {
  __builtin_amdgcn_global_load_lds(
      (const __attribute__((address_space(1))) void*)g,
      (__attribute__((address_space(3))) void*)l, 16, 0, 0);
}
#else
__device__ inline void gload16(const void* g, void* l) {
  ((float*)l)[0] = 0.f;   // unused fallback
}
#endif

// -------- pass 1: deep-ILP linear transform --------------------------------
// Wave (r, seg): owns an 8KB row segment. ALL 16 loads issued before any use
// (16 KB in flight per wave), then exp/stats/cvt, 16B stores.
__global__ __launch_bounds__(256) void transform_ilp(const float* __restrict__ vis,
                                                     const float* __restrict__ text,
                                                     ushort* __restrict__ ev,
                                                     ushort* __restrict__ et,
                                                     float* __restrict__ ws) {
  const int t = threadIdx.x, w = t >> 6, l = t & 63;
  const int W = blockIdx.x * 4 + w;     // global wave 0..8191
  const int r = W >> 3;                 // row 0..1023
  const int seg = W & 7;
  const int b = r >> 6, c = r & 63;

  const float* vseg = vis  + (size_t)r * HW + seg * 2048;
  const float* tseg = text + (size_t)r * HW + seg * 2048;
  ushort* evs = ev + (size_t)r * HW + seg * 2048;
  ushort* ets = et + (size_t)r * HW + seg * 2048;

  // lane l owns floats [8l, 8l+8) of each 512-float window; 4 windows/tensor
  f32x4 va[8], xa[8];
#pragma unroll
  for (int i = 0; i < 4; ++i) {
    va[2*i]   = *(const f32x4*)(vseg + i * 512 + 8 * l);
    va[2*i+1] = *(const f32x4*)(vseg + i * 512 + 8 * l + 4);
  }
#pragma unroll
  for (int i = 0; i < 4; ++i) {
    xa[2*i]   = *(const f32x4*)(tseg + i * 512 + 8 * l);
    xa[2*i+1] = *(const f32x4*)(tseg + i * 512 + 8 * l + 4);
  }

  float sv = 0.f, st = 0.f, ut = 0.f;
#pragma unroll
  for (int i = 0; i < 4; ++i) {
    f32x4 a0 = va[2*i], a1 = va[2*i+1];
    float e0 = __expf(a0[0]), e1 = __expf(a0[1]), e2 = __expf(a0[2]), e3 = __expf(a0[3]);
    float e4 = __expf(a1[0]), e5 = __expf(a1[1]), e6 = __expf(a1[2]), e7 = __expf(a1[3]);
    sv += ((e0 + e1) + (e2 + e3)) + ((e4 + e5) + (e6 + e7));
    u16x8 qv = { f2bf(e0), f2bf(e1), f2bf(e2), f2bf(e3),
                 f2bf(e4), f2bf(e5), f2bf(e6), f2bf(e7) };
    *reinterpret_cast<u16x8*>(evs + i * 512 + 8 * l) = qv;

    f32x4 b0 = xa[2*i], b1 = xa[2*i+1];
    float g0 = __expf(b0[0]), g1 = __expf(b0[1]), g2 = __expf(b0[2]), g3 = __expf(b0[3]);
    float g4 = __expf(b1[0]), g5 = __expf(b1[1]), g6 = __expf(b1[2]), g7 = __expf(b1[3]);
    st += ((g0 + g1) + (g2 + g3)) + ((g4 + g5) + (g6 + g7));
    ut += ((g0 * b0[0] + g1 * b0[1]) + (g2 * b0[2] + g3 * b0[3]))
        + ((g4 * b1[0] + g5 * b1[1]) + (g6 * b1[2] + g7 * b1[3]));
    u16x8 qt = { f2bf(g0), f2bf(g1), f2bf(g2), f2bf(g3),
                 f2bf(g4), f2bf(g5), f2bf(g6), f2bf(g7) };
    *reinterpret_cast<u16x8*>(ets + i * 512 + 8 * l) = qt;
  }

  sv = wave_reduce_sum(sv);
  st = wave_reduce_sum(st);
  ut = wave_reduce_sum(ut);
  if (l == 0) {
    atomicAdd(&ws[        b * 64 + c], sv);
    atomicAdd(&ws[1024 + b * 64 + c], st);
    atomicAdd(&ws[2048 + b * 64 + c], ut);
  }
}

// ---- pass 2: MFMA GEMM staging 64x64 tiles from row-major bf16 (L3-hot) ----
#define PISSUE(q) do {                                                   \
    const int k0_ = kbase + (q) * 64;                                    \
    ushort* d_ = (ushort*)sl[(q) & 3];                                   \
    _Pragma("unroll") for (int i = 0; i < 8; ++i) {                      \
      const size_t rr_ = (size_t)(rowb + i * 8 + (l >> 3));              \
      const int kk_ = k0_ + (((l & 7) ^ (l >> 3)) << 3);                 \
      gload16(evg + rr_ * HW + kk_, d_ + i * 512 + l * 8);               \
      gload16(etg + rr_ * HW + kk_, d_ + 4096 + i * 512 + l * 8);        \
    }                                                                    \
  } while (0)

#define JSTEP(p, VMC, DO_ISSUE) do {                                     \
    asm volatile("s_waitcnt vmcnt(" VMC ")" ::: "memory");               \
    __builtin_amdgcn_sched_barrier(0);                                   \
    __builtin_amdgcn_s_barrier();                                        \
    DO_ISSUE;                                                            \
    const ushort* EVp = sl[(p) & 3];                                     \
    const ushort* ETp = EVp + 4096;                                      \
    bf16x8 af[4][2];                                                     \
    _Pragma("unroll") for (int fi = 0; fi < 4; ++fi) {                   \
      af[fi][0] = *(const bf16x8*)&EVp[lds_off(fi * 16 + m16, ks0)];     \
      af[fi][1] = *(const bf16x8*)&EVp[lds_off(fi * 16 + m16, ks0 + 4)]; \
    }                                                                    \
    bf16x8 bf0 = *(const bf16x8*)&ETp[lds_off(w * 16 + m16, ks0)];       \
    bf16x8 bf1 = *(const bf16x8*)&ETp[lds_off(w * 16 + m16, ks0 + 4)];   \
    asm volatile("s_waitcnt lgkmcnt(0)" ::: "memory");                   \
    __builtin_amdgcn_sched_barrier(0);                                   \
    _Pragma("unroll") for (int fi = 0; fi < 4; ++fi) {                   \
      acc[fi] = __builtin_amdgcn_mfma_f32_16x16x32_bf16(af[fi][0], bf0, acc[fi], 0, 0, 0); \
      acc[fi] = __builtin_amdgcn_mfma_f32_16x16x32_bf16(af[fi][1], bf1, acc[fi], 0, 0, 0); \
    }                                                                    \
  } while (0)

__global__ __launch_bounds__(256) void jgemm(const ushort* __restrict__ ev,
                                             const ushort* __restrict__ et,
                                             float* __restrict__ ws, int jmask) {
  const int b = blockIdx.x >> 5, chunk = blockIdx.x & 31;   // 512 blocks
  const int t = threadIdx.x, w = t >> 6, l = t & 63;
  const int m16 = l & 15, ks0 = l >> 4;
  const int rowb = b * 64;
  const int kbase = chunk * 512;

  __shared__ ushort sl[4][8192];        // 4 slots x (ev tile | et tile)

  const ushort* evg = ev;
  const ushort* etg = et;

  f32x4 acc[4];
#pragma unroll
  for (int i = 0; i < 4; ++i) acc[i] = (f32x4){0.f, 0.f, 0.f, 0.f};

  PISSUE(0); PISSUE(1); PISSUE(2);      // 48 loads in flight

  JSTEP(0, "32", PISSUE(3));
  JSTEP(1, "32", PISSUE(4));
  JSTEP(2, "32", PISSUE(5));
  JSTEP(3, "32", PISSUE(6));
  JSTEP(4, "32", PISSUE(7));
  JSTEP(5, "32", (void)0);
  JSTEP(6, "16", (void)0);
  JSTEP(7, "0",  (void)0);

  // C/D layout: col = l&15, row = (l>>4)*4 + reg (verified R2/R4/R5/R7)
  float* Jp = ws + 4096 + (size_t)((chunk & jmask) * NB + b) * 4096;
  const int q4 = (l >> 4) * 4;
#pragma unroll
  for (int fi = 0; fi < 4; ++fi)
#pragma unroll
    for (int r = 0; r < 4; ++r)
      atomicAdd(&Jp[(fi * 16 + q4 + r) * 64 + w * 16 + m16], acc[fi][r]);
}

// ---------------- pass 3: MI + guide weights -------------------------------
__global__ __launch_bounds__(256) void mi_gw_kernel(const float* __restrict__ ws,
                                                    float* __restrict__ gw,
                                                    int npart) {
  const int b = blockIdx.x, t = threadIdx.x;
  __shared__ float sSv[64], sSt[64];
  if (t < 64) sSv[t] = ws[b * 64 + t];
  else if (t < 128) sSt[t - 64] = ws[1024 + b * 64 + (t - 64)];
  __syncthreads();

  f32x4 jr0 = {0,0,0,0}, jr1 = {0,0,0,0}, jr2 = {0,0,0,0}, jr3 = {0,0,0,0};
  const float* base = ws + 4096 + (size_t)b * 4096 + t * 16;
  for (int p = 0; p < npart; ++p) {
    const f32x4* cp = (const f32x4*)(base + (size_t)p * (NB * 4096));
    jr0 += cp[0]; jr1 += cp[1]; jr2 += cp[2]; jr3 += cp[3];
  }

  const float HW2 = (float)HW * (float)HW;
  const float fv = HW2 / sSv[t >> 2];
  const int d0 = (t & 3) * 16;
  float part = 0.f;
#pragma unroll
  for (int j = 0; j < 16; ++j) {
    float jv = (j < 4) ? jr0[j] : (j < 8) ? jr1[j - 4] : (j < 12) ? jr2[j - 8] : jr3[j - 12];
    float q = jv * (fv / sSt[d0 + j]);
    part += q * __logf(q + 1e-9f);
  }
  part = wave_reduce_sum(part);
  __shared__ float sh[4];
  __shared__ float mi_sh;
  int wid = t >> 6, lane = t & 63;
  if (lane == 0) sh[wid] = part;
  __syncthreads();
  if (t == 0) mi_sh = ((sh[0] + sh[1]) + (sh[2] + sh[3])) / HW2;
  __syncthreads();
  if (t < 64) {
    float S = sSt[t];
    float U = ws[2048 + b * 64 + t];
    float ent = __logf(S) - U / S;               // text spatial entropy
    float z = 1.0f - ent + 0.5f * mi_sh;
    gw[b * 64 + t] = 1.0f / (1.0f + __expf(-z));
  }
}

// ---------------- pass 4: deep-ILP enhance ---------------------------------
// Wave (r, seg): gw[r] is wave-uniform; 16 loads issued up front, then fma+store.
__global__ __launch_bounds__(256) void enhance_ilp(const float* __restrict__ vis,
                                                   const float* __restrict__ text,
                                                   const float* __restrict__ gw,
                                                   float* __restrict__ out) {
  const int t = threadIdx.x, w = t >> 6, l = t & 63;
  const int W = blockIdx.x * 4 + w;
  const int r = W >> 3;
  const int seg = W & 7;

  const float g = gw[r];
  const f32x4* vseg = (const f32x4*)(vis  + (size_t)r * HW + seg * 2048);
  const f32x4* tseg = (const f32x4*)(text + (size_t)r * HW + seg * 2048);
  f32x4* oseg = (f32x4*)(out + (size_t)r * HW + seg * 2048);

  f32x4 va[8], xa[8];
#pragma unroll
  for (int i = 0; i < 8; ++i) va[i] = vseg[i * 64 + l];
#pragma unroll
  for (int i = 0; i < 8; ++i) xa[i] = tseg[i * 64 + l];
#pragma unroll
  for (int i = 0; i < 8; ++i) {
    f32x4 o;
    o[0] = va[i][0] + g * xa[i][0];
    o[1] = va[i][1] + g * xa[i][1];
    o[2] = va[i][2] + g * xa[i][2];
    o[3] = va[i][3] + g * xa[i][3];
    oseg[i * 64 + l] = o;
  }
}

extern "C" void kernel_launch(void* const* d_in, const int* in_sizes, int n_in,
                              void* d_out, int out_size, void* d_ws, size_t ws_size,
                              hipStream_t stream) {
  const float* vis  = (const float*)d_in[0];
  const float* text = (const float*)d_in[1];
  float* out = (float*)d_out;
  float* ws  = (float*)d_ws;
  float* gw  = ws + 3072;

  // d_out doubles as the bf16 exp matrices (fully overwritten by enhance)
  ushort* ev = (ushort*)d_out;
  ushort* et = ev + (size_t)1024 * HW;   // +32 MB

  size_t ws_floats = ws_size / sizeof(float);
  int npart = 1;
  if      (ws_floats >= 4096 + 4 * 65536) npart = 4;
  else if (ws_floats >= 4096 + 2 * 65536) npart = 2;

  hipMemsetAsync(ws, 0, (4096 + (size_t)npart * 65536) * sizeof(float), stream);

  transform_ilp<<<2048, 256, 0, stream>>>(vis, text, ev, et, ws);
  jgemm<<<512, 256, 0, stream>>>(ev, et, ws, npart - 1);
  mi_gw_kernel<<<NB, 256, 0, stream>>>(ws, gw, npart);
  enhance_ilp<<<2048, 256, 0, stream>>>(vis, text, gw, out);
}